// Round 12
// baseline (971.194 us; speedup 1.0000x reference)
//
#include <hip/hip_runtime.h>

typedef __bf16 bf16_t;
typedef bf16_t bf16x8 __attribute__((ext_vector_type(8)));
typedef float  f32x4  __attribute__((ext_vector_type(4)));

#define MFMA16(A, B, C) __builtin_amdgcn_mfma_f32_16x16x32_bf16((A), (B), (C), 0, 0, 0)

static constexpr int KEXT   = 288;  // 256 h | 3 x | 1 ones(bias) | 28 zero pad
static constexpr int HS     = 296;  // hx LDS row stride
static constexpr int GS     = 264;  // gate-g LDS tile stride
static constexpr int TSTEPS = 128;
static constexpr int TILE_B = 16;   // grid 256 -> 1 block/CU

// ws layout (bf16 elements)
static constexpr int WALL_OFF = 0;                    // [1152][288] gates(1024) + Wo1ext(128)
static constexpr int W2E_OFF  = 1152 * 288;           // [512][288]  encoder layer2 (+b2 col)
static constexpr int WO2E_OFF = W2E_OFF + 512 * 288;  // [16][128]   Wo2 padded
static constexpr int WS_ELEMS = WO2E_OFF + 16 * 128;

// ---------------- prep: pack weights bf16 (ws re-poisoned every launch) ----------------
__global__ __launch_bounds__(256) void prep_kernel(
    const float* __restrict__ W2,  const float* __restrict__ b2,
    const float* __restrict__ Wih, const float* __restrict__ Whh,
    const float* __restrict__ bih, const float* __restrict__ bhh,
    const float* __restrict__ Wo1, const float* __restrict__ bo1,
    const float* __restrict__ Wo2, bf16_t* __restrict__ ws)
{
    int idx = blockIdx.x * 256 + threadIdx.x;
    if (idx < 1152 * 288) {
        int r = idx / 288, k = idx - r * 288;
        float v = 0.f;
        if (r < 1024) {                       // gate rows: i f g o (256 each)
            if (k < 256)       v = Whh[r * 256 + k];
            else if (k < 259)  v = Wih[r * 3 + (k - 256)];
            else if (k == 259) v = bih[r] + bhh[r];
        } else {                              // Wo1 rows (zeros at x cols, bo1 at ones col)
            int q = r - 1024;
            if (k < 256)       v = Wo1[q * 256 + k];
            else if (k == 259) v = bo1[q];
        }
        ws[WALL_OFF + idx] = (bf16_t)v;
    } else if (idx < W2E_OFF + 512 * 288) {
        int j = idx - W2E_OFF;
        int u = j / 288, k = j - u * 288;
        float v = 0.f;
        if (k < 256)       v = W2[u * 256 + k];
        else if (k == 259) v = b2[u];
        ws[idx] = (bf16_t)v;
    } else if (idx < WS_ELEMS) {
        int j = idx - WO2E_OFF;
        int d = j >> 7, q = j & 127;
        ws[idx] = (bf16_t)((d < 3) ? Wo2[d * 128 + q] : 0.f);
    }
}

// v_rcp_f32 (1 ulp): validated R8/R9 — absmax unchanged (4.88e-4).
__device__ __forceinline__ float rcp_f(float x) {
    float r; asm("v_rcp_f32 %0, %1" : "=v"(r) : "v"(x)); return r;
}
__device__ __forceinline__ float sigm(float x) { return rcp_f(1.f + __expf(-x)); }
// No clamp needed with the rcp form: x->+inf -> 1, x->-inf -> -1, both exact.
__device__ __forceinline__ float tanh_f(float x) {
    float e = __expf(2.f * x);
    return 1.f - 2.f * rcp_f(e + 1.f);   // == (e-1)/(e+1)
}
__device__ __forceinline__ unsigned pk2(float a, float b) {
    union { bf16_t h[2]; unsigned u; } x;
    x.h[0] = (bf16_t)a; x.h[1] = (bf16_t)b; return x.u;
}

// Raw barrier: LDS visibility only (lgkmcnt drain), NO vmcnt drain -> global prefetches
// survive barriers (R7's key fix; __syncthreads' vmcnt(0) drain killed every prefetch).
__device__ __forceinline__ void bar_lds() {
    asm volatile("s_waitcnt lgkmcnt(0)" ::: "memory");
    __builtin_amdgcn_s_barrier();
}

// ---------------- main: 256 blocks x 512 thr (8 waves); block owns 16 batches.
// R11 structure (640 us) + explicit LDS software-pipelining (the compiler can't hoist
// at ~240/256 reg pressure, so we do it by hand in the phases that have slack):
//   G  : bfb[2]/agb[2][2] double buffer -- slice kk+1's 3 ds_reads issue BEFORE slice
//        kk's MFMAs; kk=0 operands prefetched at end of previous Y (h_{i+1} readable
//        since B1; no barrier between Y and G).
//   Z  : zb[3] rolling same-slot distance-3; first 3 reads burst right after B1.
//   Y  : all 8 reads batched before the MFMAs.
//   o  : 9-slice stream, 3-slot carried ring, same-slot consume-then-refill distance-3.
//   Wo1: full 9-slice wrf burst in cell (R10). i,f: af[2][2][9] resident (144 VGPR).
// Canary: FETCH_SIZE. If regalloc tips (R8 remat signature) FETCH jumps >=1e5 KB.
__global__ __launch_bounds__(512, 2) void lstm_main(
    const float* __restrict__ meta, const float* __restrict__ W1,
    const float* __restrict__ b1,   const float* __restrict__ bo2,
    const bf16_t* __restrict__ ws,  float* __restrict__ out)
{
    __shared__ __align__(16) bf16_t hx[2][TILE_B][HS];  // h buffers; ext cols [0,0,0,1,pad]
    __shared__ __align__(16) bf16_t wg[256][GS];        // gate g weights; aliased as cbuf in setup
    __shared__ __align__(16) bf16_t wo2l[16][136];
    __shared__ __align__(16) bf16_t zbuf[TILE_B][136];

    const int tid  = threadIdx.x;
    const int wv   = tid >> 6;       // 0..7
    const int lane = tid & 63;
    const int l15  = lane & 15;
    const int quad = lane >> 4;      // 0..3
    const int gb   = blockIdx.x * TILE_B;

    const bf16_t* wall = ws + WALL_OFF;
    const bf16_t* w2e  = ws + W2E_OFF;
    const bf16_t* wo2e = ws + WO2E_OFF;
    const f32x4 zero4 = {0.f, 0.f, 0.f, 0.f};

    // ---- init ext cols of both hx buffers: zeros, ones col (z-bias via Wo1ext) ----
    if (tid < 32) {
        int buf = tid >> 4, b = tid & 15;
        for (int c2 = 256; c2 < HS; ++c2)
            hx[buf][b][c2] = (bf16_t)((c2 == 259) ? 1.f : 0.f);
    }
    // ---- enc1 (VALU, K=7) into hx[1] ----
    {
        int b = tid & 15, j0 = (tid >> 4) * 8;
        float m[7];
        #pragma unroll
        for (int k = 0; k < 7; ++k) m[k] = meta[(size_t)(gb + b) * 7 + k];
        #pragma unroll
        for (int jj = 0; jj < 8; ++jj) {
            int jd = j0 + jj;
            float acc = b1[jd];
            #pragma unroll
            for (int k = 0; k < 7; ++k) acc += W1[jd * 7 + k] * m[k];
            hx[1][b][jd] = (bf16_t)fmaxf(acc, 0.f);
        }
    }
    __syncthreads();

    // ---- enc2 via MFMA: wave wv rows [64wv,64wv+64); rows<256 -> h0(hx[0]), >=256 -> c0(cbuf) ----
    float* cbuf = (float*)&wg[0][0];  // fp32 [256][17] staging inside wg space
    {
        f32x4 e[4] = {zero4, zero4, zero4, zero4};
        #pragma unroll
        for (int kk = 0; kk < 9; ++kk) {
            int ko = 32 * kk + 8 * quad;
            bf16x8 bf = *(const bf16x8*)&hx[1][l15][ko];
            #pragma unroll
            for (int m = 0; m < 4; ++m) {
                bf16x8 aa = *(const bf16x8*)&w2e[(size_t)(64 * wv + 16 * m + l15) * KEXT + ko];
                e[m] = MFMA16(aa, bf, e[m]);
            }
        }
        #pragma unroll
        for (int m = 0; m < 4; ++m) {
            int row = 64 * wv + 16 * m + 4 * quad;
            if (row < 256) {  // h0
                *(unsigned*)&hx[0][l15][row]     = pk2(fmaxf(e[m][0], 0.f), fmaxf(e[m][1], 0.f));
                *(unsigned*)&hx[0][l15][row + 2] = pk2(fmaxf(e[m][2], 0.f), fmaxf(e[m][3], 0.f));
            } else {          // c0
                int d = row - 256;
                #pragma unroll
                for (int r = 0; r < 4; ++r)
                    cbuf[(size_t)(d + r) * 17 + l15] = fmaxf(e[m][r], 0.f);
            }
        }
    }
    __syncthreads();

    // ---- c0 -> regs: c[half][r] at dim 32wv+16half+4quad+r, batch l15 ----
    f32x4 c[2];
    #pragma unroll
    for (int half = 0; half < 2; ++half)
        #pragma unroll
        for (int r = 0; r < 4; ++r)
            c[half][r] = cbuf[(size_t)(32 * wv + 16 * half + 4 * quad + r) * 17 + l15];
    __syncthreads();

    // ---- gate g -> LDS (overwrites cbuf); Wo2 -> LDS ----
    #pragma unroll
    for (int i = 0; i < 17; ++i) {
        int idx = tid + 512 * i;
        if (idx < 256 * 33) {
            int r = idx / 33, c8 = idx - r * 33;
            *(bf16x8*)&wg[r][8 * c8] = *(const bf16x8*)&wall[(size_t)(512 + r) * KEXT + 8 * c8];
        }
    }
    #pragma unroll
    for (int i = 0; i < 2; ++i) {
        int idx = tid + 512 * i;
        if (idx < 16 * 128) {
            int r = idx >> 7, cc = idx & 127;
            wo2l[r][cc] = wo2e[r * 128 + cc];
        }
    }

    // ---- resident A-frags: gates i,f for dims [32wv,32wv+32): af[g][half][kk] = 144 VGPR ----
    bf16x8 af[2][2][9];
    #pragma unroll
    for (int g = 0; g < 2; ++g)
        #pragma unroll
        for (int h = 0; h < 2; ++h)
            #pragma unroll
            for (int kk = 0; kk < 9; ++kk)
                af[g][h][kk] = *(const bf16x8*)&wall[(size_t)(256 * g + 32 * wv + 16 * h + l15) * KEXT
                                                     + 32 * kk + 8 * quad];

    // ---- stream bases (t-invariant addresses) ----
    const bf16_t* obase = wall + (size_t)(768  + 32 * wv + l15) * KEXT + 8 * quad;  // gate o
    const bf16_t* wbase = wall + (size_t)(1024 + 16 * wv + l15) * KEXT + 8 * quad;  // Wo1

    const float bo2v0 = bo2[0], bo2v1 = bo2[1], bo2v2 = bo2[2];

    // ---- ob ring (carried): prefill slices 0,1,2 -> slots 0,1,2 ----
    bf16x8 ob[3][2];
    #pragma unroll
    for (int s = 0; s < 3; ++s)
        #pragma unroll
        for (int h = 0; h < 2; ++h)
            ob[s][h] = *(const bf16x8*)(obase + (size_t)(16 * h) * KEXT + 32 * s);

    // ---- x_0 fragment in regs: quad0 = {m0,m1,m2,1,0..}, quads 1..3 = 0 ----
    bf16x8 xf;
    #pragma unroll
    for (int j = 0; j < 8; ++j) xf[j] = (bf16_t)0.f;
    if (quad == 0) {
        xf[0] = (bf16_t)meta[(size_t)(gb + l15) * 7 + 0];
        xf[1] = (bf16_t)meta[(size_t)(gb + l15) * 7 + 1];
        xf[2] = (bf16_t)meta[(size_t)(gb + l15) * 7 + 2];
        xf[3] = (bf16_t)1.f;
    }

    __syncthreads();   // wg/wo2l ready (one-time full sync is fine here)

    // ---- G-phase LDS prefetch buffers (carried Y -> G): preload i=0, kk=0 operands ----
    bf16x8 bfb[2], agb[2][2];
    bfb[0]    = *(const bf16x8*)&hx[0][l15][8 * quad];
    agb[0][0] = *(const bf16x8*)&wg[32 * wv + l15][8 * quad];
    agb[0][1] = *(const bf16x8*)&wg[32 * wv + 16 + l15][8 * quad];

    // ================= time loop: G (gates+cell+wrf burst) -> B1 -> Z -> B2 -> Y ======
    for (int i = 0; i < TSTEPS; ++i) {
        const bf16_t (*cur)[HS] = hx[i & 1];         // h_i
        bf16_t (*nxt)[HS]       = hx[(i + 1) & 1];   // h_{i+1} destination

        // -- G: gates_i = [h_i|x_i|1] @ Wall^T; kk<8 B from LDS (1-ahead prefetched),
        //       kk=8 B = xf regs. ob: same-slot consume-then-refill distance-3. --
        f32x4 acc[4][2];
        #pragma unroll
        for (int g = 0; g < 4; ++g) { acc[g][0] = zero4; acc[g][1] = zero4; }

        #pragma unroll
        for (int kk = 0; kk < 9; ++kk) {
            const int cb = kk & 1, nb = cb ^ 1;
            // prefetch slice kk+1 operands (issued before this slice's MFMAs; the
            // lgkmcnt wait before the MFMAs is counted, so these stay in flight)
            if (kk < 8) {
                int ko1 = 32 * (kk + 1) + 8 * quad;
                if (kk + 1 < 8)
                    bfb[nb] = *(const bf16x8*)&cur[l15][ko1];
                agb[nb][0] = *(const bf16x8*)&wg[32 * wv + l15][ko1];
                agb[nb][1] = *(const bf16x8*)&wg[32 * wv + 16 + l15][ko1];
            }
            bf16x8 bfc = (kk < 8) ? bfb[cb] : xf;
            #pragma unroll
            for (int h = 0; h < 2; ++h) {
                // kk=8: ag read past col 263 aliases next row's cols; B zero there -> harmless
                acc[0][h] = MFMA16(af[0][h][kk], bfc, acc[0][h]);
                acc[1][h] = MFMA16(af[1][h][kk], bfc, acc[1][h]);
                acc[2][h] = MFMA16(agb[cb][h],   bfc, acc[2][h]);
                acc[3][h] = MFMA16(ob[kk % 3][h], bfc, acc[3][h]);
            }
            // refill consumed ob slot with slice (kk+3)%9 (WAR orders load after MFMAs;
            // kk=6,7,8 load next-t slices 0,1,2 -> cross-barrier slack)
            #pragma unroll
            for (int h = 0; h < 2; ++h)
                ob[kk % 3][h] = *(const bf16x8*)(obase + (size_t)(16 * h) * KEXT
                                                 + 32 * ((kk + 3) % 9));
        }

        // -- cell update (regs) + write h_{i+1}; wrf burst issued mid-cell (acc dying,
        //    loads get cell+barrier+Z-ramp of slack before first consume) --
        bf16x8 wrf[9];
        {
            // half 0
            float hh[4];
            #pragma unroll
            for (int r = 0; r < 4; ++r) {
                float iv = acc[0][0][r], fv = acc[1][0][r];
                float gv = acc[2][0][r], ov = acc[3][0][r];
                float cc = sigm(fv) * c[0][r] + sigm(iv) * tanh_f(gv);
                c[0][r] = cc;
                hh[r] = sigm(ov) * tanh_f(cc);
            }
            int dim = 32 * wv + 4 * quad;
            *(unsigned*)&nxt[l15][dim]     = pk2(hh[0], hh[1]);
            *(unsigned*)&nxt[l15][dim + 2] = pk2(hh[2], hh[3]);
        }
        #pragma unroll
        for (int s = 0; s < 5; ++s) wrf[s] = *(const bf16x8*)(wbase + 32 * s);
        {
            // half 1
            float hh[4];
            #pragma unroll
            for (int r = 0; r < 4; ++r) {
                float iv = acc[0][1][r], fv = acc[1][1][r];
                float gv = acc[2][1][r], ov = acc[3][1][r];
                float cc = sigm(fv) * c[1][r] + sigm(iv) * tanh_f(gv);
                c[1][r] = cc;
                hh[r] = sigm(ov) * tanh_f(cc);
            }
            int dim = 32 * wv + 16 + 4 * quad;
            *(unsigned*)&nxt[l15][dim]     = pk2(hh[0], hh[1]);
            *(unsigned*)&nxt[l15][dim + 2] = pk2(hh[2], hh[3]);
        }
        #pragma unroll
        for (int s = 5; s < 9; ++s) wrf[s] = *(const bf16x8*)(wbase + 32 * s);
        bar_lds();   // B1: h_{i+1} visible; wrf/ob loads stay in flight

        // -- Z: z_i = relu(h_{i+1} @ Wo1ext^T); wave wv -> z-dims [16wv,16wv+16).
        //       Wo1 from wrf (NO global loads); zb[3] rolling same-slot distance-3
        //       (first 3 reads burst immediately after B1); za 2 parallel chains --
        {
            bf16x8 zb[3];
            #pragma unroll
            for (int s = 0; s < 3; ++s)
                zb[s] = *(const bf16x8*)&nxt[l15][32 * s + 8 * quad];
            f32x4 za0 = zero4, za1 = zero4;
            #pragma unroll
            for (int kk = 0; kk < 9; ++kk) {
                if (kk & 1) za1 = MFMA16(wrf[kk], zb[kk % 3], za1);
                else        za0 = MFMA16(wrf[kk], zb[kk % 3], za0);
                if (kk + 3 <= 8)
                    zb[kk % 3] = *(const bf16x8*)&nxt[l15][32 * (kk + 3) + 8 * quad];
            }
            f32x4 za = za0 + za1;
            int zd = 16 * wv + 4 * quad;
            *(unsigned*)&zbuf[l15][zd]     = pk2(fmaxf(za[0], 0.f), fmaxf(za[1], 0.f));
            *(unsigned*)&zbuf[l15][zd + 2] = pk2(fmaxf(za[2], 0.f), fmaxf(za[3], 0.f));
        }
        bar_lds();   // B2: z complete

        // -- Y: ALL waves redundantly y_i = z @ Wo2ext^T (batched reads, 2 chains);
        //       xf <- x_{i+1}; rotate out-store; prefetch next-G kk=0 operands.
        //       No trailing barrier (Y touches only zbuf/wo2l; hazards via B1/B2). --
        {
            bf16x8 w2b[4], zbb[4];
            #pragma unroll
            for (int kk = 0; kk < 4; ++kk) {
                int ko = 32 * kk + 8 * quad;
                w2b[kk] = *(const bf16x8*)&wo2l[l15][ko];
                zbb[kk] = *(const bf16x8*)&zbuf[l15][ko];
            }
            f32x4 ya0 = zero4, ya1 = zero4;
            #pragma unroll
            for (int kk = 0; kk < 4; ++kk) {
                if (kk & 2) ya1 = MFMA16(w2b[kk], zbb[kk], ya1);
                else        ya0 = MFMA16(w2b[kk], zbb[kk], ya0);
            }
            f32x4 yv = ya0 + ya1;
            float y0 = yv[0] + bo2v0, y1 = yv[1] + bo2v1, y2 = yv[2] + bo2v2;
            if (wv == (i & 7) && quad == 0) {   // rotate storer: ack never blocks a barrier
                float* op = out + ((size_t)(gb + l15) * TSTEPS + i) * 3;
                op[0] = y0; op[1] = y1; op[2] = y2;
            }
            if (quad == 0) {
                xf[0] = (bf16_t)y0; xf[1] = (bf16_t)y1; xf[2] = (bf16_t)y2; xf[3] = (bf16_t)1.f;
            }
            // prefetch next-G kk=0 operands (h_{i+1} = hx[(i+1)&1], readable since B1)
            const bf16_t (*nc)[HS] = hx[(i + 1) & 1];
            bfb[0]    = *(const bf16x8*)&nc[l15][8 * quad];
            agb[0][0] = *(const bf16x8*)&wg[32 * wv + l15][8 * quad];
            agb[0][1] = *(const bf16x8*)&wg[32 * wv + 16 + l15][8 * quad];
        }
    }
}

extern "C" void kernel_launch(void* const* d_in, const int* in_sizes, int n_in,
                              void* d_out, int out_size, void* d_ws, size_t ws_size,
                              hipStream_t stream)
{
    const float* meta = (const float*)d_in[0];
    const float* W1   = (const float*)d_in[2];
    const float* b1   = (const float*)d_in[3];
    const float* W2   = (const float*)d_in[4];
    const float* b2   = (const float*)d_in[5];
    const float* Wih  = (const float*)d_in[6];
    const float* Whh  = (const float*)d_in[7];
    const float* bih  = (const float*)d_in[8];
    const float* bhh  = (const float*)d_in[9];
    const float* Wo1  = (const float*)d_in[10];
    const float* bo1  = (const float*)d_in[11];
    const float* Wo2  = (const float*)d_in[12];
    const float* bo2  = (const float*)d_in[13];
    bf16_t* ws  = (bf16_t*)d_ws;
    float*  out = (float*)d_out;

    prep_kernel<<<dim3((WS_ELEMS + 255) / 256), dim3(256), 0, stream>>>(
        W2, b2, Wih, Whh, bih, bhh, Wo1, bo1, Wo2, ws);
    lstm_main<<<dim3(4096 / TILE_B), dim3(512), 0, stream>>>(
        meta, W1, b1, bo2, ws, out);
}

// Round 13
// 631.739 us; speedup vs baseline: 1.5373x; 1.5373x over previous
//
#include <hip/hip_runtime.h>

typedef __bf16 bf16_t;
typedef bf16_t bf16x8 __attribute__((ext_vector_type(8)));
typedef float  f32x4  __attribute__((ext_vector_type(4)));

#define MFMA16(A, B, C) __builtin_amdgcn_mfma_f32_16x16x32_bf16((A), (B), (C), 0, 0, 0)

static constexpr int KEXT   = 288;  // 256 h | 3 x | 1 ones(bias) | 28 zero pad
static constexpr int HS     = 296;  // hx LDS row stride
static constexpr int GS     = 264;  // gate-g LDS tile stride
static constexpr int TSTEPS = 128;
static constexpr int TILE_B = 16;   // grid 256 -> 1 block/CU

// ws layout (bf16 elements)
static constexpr int WALL_OFF = 0;                    // [1152][288] gates(1024) + Wo1ext(128)
static constexpr int W2E_OFF  = 1152 * 288;           // [512][288]  encoder layer2 (+b2 col)
static constexpr int WO2E_OFF = W2E_OFF + 512 * 288;  // [16][128]   Wo2 padded
static constexpr int WS_ELEMS = WO2E_OFF + 16 * 128;

// ---------------- prep: pack weights bf16 (ws re-poisoned every launch) ----------------
__global__ __launch_bounds__(256) void prep_kernel(
    const float* __restrict__ W2,  const float* __restrict__ b2,
    const float* __restrict__ Wih, const float* __restrict__ Whh,
    const float* __restrict__ bih, const float* __restrict__ bhh,
    const float* __restrict__ Wo1, const float* __restrict__ bo1,
    const float* __restrict__ Wo2, bf16_t* __restrict__ ws)
{
    int idx = blockIdx.x * 256 + threadIdx.x;
    if (idx < 1152 * 288) {
        int r = idx / 288, k = idx - r * 288;
        float v = 0.f;
        if (r < 1024) {                       // gate rows: i f g o (256 each)
            if (k < 256)       v = Whh[r * 256 + k];
            else if (k < 259)  v = Wih[r * 3 + (k - 256)];
            else if (k == 259) v = bih[r] + bhh[r];
        } else {                              // Wo1 rows (zeros at x cols, bo1 at ones col)
            int q = r - 1024;
            if (k < 256)       v = Wo1[q * 256 + k];
            else if (k == 259) v = bo1[q];
        }
        ws[WALL_OFF + idx] = (bf16_t)v;
    } else if (idx < W2E_OFF + 512 * 288) {
        int j = idx - W2E_OFF;
        int u = j / 288, k = j - u * 288;
        float v = 0.f;
        if (k < 256)       v = W2[u * 256 + k];
        else if (k == 259) v = b2[u];
        ws[idx] = (bf16_t)v;
    } else if (idx < WS_ELEMS) {
        int j = idx - WO2E_OFF;
        int d = j >> 7, q = j & 127;
        ws[idx] = (bf16_t)((d < 3) ? Wo2[d * 128 + q] : 0.f);
    }
}

// v_rcp_f32 (1 ulp): validated R8/R9 — absmax unchanged (4.88e-4).
__device__ __forceinline__ float rcp_f(float x) {
    float r; asm("v_rcp_f32 %0, %1" : "=v"(r) : "v"(x)); return r;
}
__device__ __forceinline__ float sigm(float x) { return rcp_f(1.f + __expf(-x)); }
// No clamp needed with the rcp form: x->+inf -> 1, x->-inf -> -1, both exact.
__device__ __forceinline__ float tanh_f(float x) {
    float e = __expf(2.f * x);
    return 1.f - 2.f * rcp_f(e + 1.f);   // == (e-1)/(e+1)
}
__device__ __forceinline__ unsigned pk2(float a, float b) {
    union { bf16_t h[2]; unsigned u; } x;
    x.h[0] = (bf16_t)a; x.h[1] = (bf16_t)b; return x.u;
}

// Raw barrier: LDS visibility only (lgkmcnt drain), NO vmcnt drain -> global prefetches
// survive barriers (R7's key fix; __syncthreads' vmcnt(0) drain killed every prefetch).
__device__ __forceinline__ void bar_lds() {
    asm volatile("s_waitcnt lgkmcnt(0)" ::: "memory");
    __builtin_amdgcn_s_barrier();
}

// ---------------- main: 256 blocks x 512 thr (8 waves); block owns 16 batches.
// G phase = R11 EXACTLY (640 us config). R12's lesson: G has ZERO carried-register
// headroom -- its +24-reg carried double-buffer (bfb/agb across the Y->G back edge)
// tipped the 256-reg cap -> af remat (FETCH 14.7e3 -> 210e3 KB). Only TRANSIENT
// registers in slack phases are allowed:
//   Z : zb[3] rolling same-slot distance-3 LDS prefetch (12 regs, live B1->B2 only)
//   Y : batched 8 LDS reads before MFMAs (32 regs, live B2->loop-end only)
// Everything else unchanged from R11:
//   i,f : VGPR-resident af[2][2][9] (144); g LDS wg[256][264]; o same-slot distance-3
//   carried ring; Wo1 full wrf[9] burst mid-cell; 2 raw barriers/t.
// Canary: FETCH_SIZE must return to ~1.5e4 KB.
__global__ __launch_bounds__(512, 2) void lstm_main(
    const float* __restrict__ meta, const float* __restrict__ W1,
    const float* __restrict__ b1,   const float* __restrict__ bo2,
    const bf16_t* __restrict__ ws,  float* __restrict__ out)
{
    __shared__ __align__(16) bf16_t hx[2][TILE_B][HS];  // h buffers; ext cols [0,0,0,1,pad]
    __shared__ __align__(16) bf16_t wg[256][GS];        // gate g weights; aliased as cbuf in setup
    __shared__ __align__(16) bf16_t wo2l[16][136];
    __shared__ __align__(16) bf16_t zbuf[TILE_B][136];

    const int tid  = threadIdx.x;
    const int wv   = tid >> 6;       // 0..7
    const int lane = tid & 63;
    const int l15  = lane & 15;
    const int quad = lane >> 4;      // 0..3
    const int gb   = blockIdx.x * TILE_B;

    const bf16_t* wall = ws + WALL_OFF;
    const bf16_t* w2e  = ws + W2E_OFF;
    const bf16_t* wo2e = ws + WO2E_OFF;
    const f32x4 zero4 = {0.f, 0.f, 0.f, 0.f};

    // ---- init ext cols of both hx buffers: zeros, ones col (z-bias via Wo1ext) ----
    if (tid < 32) {
        int buf = tid >> 4, b = tid & 15;
        for (int c2 = 256; c2 < HS; ++c2)
            hx[buf][b][c2] = (bf16_t)((c2 == 259) ? 1.f : 0.f);
    }
    // ---- enc1 (VALU, K=7) into hx[1] ----
    {
        int b = tid & 15, j0 = (tid >> 4) * 8;
        float m[7];
        #pragma unroll
        for (int k = 0; k < 7; ++k) m[k] = meta[(size_t)(gb + b) * 7 + k];
        #pragma unroll
        for (int jj = 0; jj < 8; ++jj) {
            int jd = j0 + jj;
            float acc = b1[jd];
            #pragma unroll
            for (int k = 0; k < 7; ++k) acc += W1[jd * 7 + k] * m[k];
            hx[1][b][jd] = (bf16_t)fmaxf(acc, 0.f);
        }
    }
    __syncthreads();

    // ---- enc2 via MFMA: wave wv rows [64wv,64wv+64); rows<256 -> h0(hx[0]), >=256 -> c0(cbuf) ----
    float* cbuf = (float*)&wg[0][0];  // fp32 [256][17] staging inside wg space
    {
        f32x4 e[4] = {zero4, zero4, zero4, zero4};
        #pragma unroll
        for (int kk = 0; kk < 9; ++kk) {
            int ko = 32 * kk + 8 * quad;
            bf16x8 bf = *(const bf16x8*)&hx[1][l15][ko];
            #pragma unroll
            for (int m = 0; m < 4; ++m) {
                bf16x8 aa = *(const bf16x8*)&w2e[(size_t)(64 * wv + 16 * m + l15) * KEXT + ko];
                e[m] = MFMA16(aa, bf, e[m]);
            }
        }
        #pragma unroll
        for (int m = 0; m < 4; ++m) {
            int row = 64 * wv + 16 * m + 4 * quad;
            if (row < 256) {  // h0
                *(unsigned*)&hx[0][l15][row]     = pk2(fmaxf(e[m][0], 0.f), fmaxf(e[m][1], 0.f));
                *(unsigned*)&hx[0][l15][row + 2] = pk2(fmaxf(e[m][2], 0.f), fmaxf(e[m][3], 0.f));
            } else {          // c0
                int d = row - 256;
                #pragma unroll
                for (int r = 0; r < 4; ++r)
                    cbuf[(size_t)(d + r) * 17 + l15] = fmaxf(e[m][r], 0.f);
            }
        }
    }
    __syncthreads();

    // ---- c0 -> regs: c[half][r] at dim 32wv+16half+4quad+r, batch l15 ----
    f32x4 c[2];
    #pragma unroll
    for (int half = 0; half < 2; ++half)
        #pragma unroll
        for (int r = 0; r < 4; ++r)
            c[half][r] = cbuf[(size_t)(32 * wv + 16 * half + 4 * quad + r) * 17 + l15];
    __syncthreads();

    // ---- gate g -> LDS (overwrites cbuf); Wo2 -> LDS ----
    #pragma unroll
    for (int i = 0; i < 17; ++i) {
        int idx = tid + 512 * i;
        if (idx < 256 * 33) {
            int r = idx / 33, c8 = idx - r * 33;
            *(bf16x8*)&wg[r][8 * c8] = *(const bf16x8*)&wall[(size_t)(512 + r) * KEXT + 8 * c8];
        }
    }
    #pragma unroll
    for (int i = 0; i < 4; ++i) {
        int idx = tid + 512 * i;
        int r = idx >> 7, cc = idx & 127;
        wo2l[r][cc] = wo2e[r * 128 + cc];
    }

    // ---- resident A-frags: gates i,f for dims [32wv,32wv+32): af[g][half][kk] = 144 VGPR ----
    bf16x8 af[2][2][9];
    #pragma unroll
    for (int g = 0; g < 2; ++g)
        #pragma unroll
        for (int h = 0; h < 2; ++h)
            #pragma unroll
            for (int kk = 0; kk < 9; ++kk)
                af[g][h][kk] = *(const bf16x8*)&wall[(size_t)(256 * g + 32 * wv + 16 * h + l15) * KEXT
                                                     + 32 * kk + 8 * quad];

    // ---- stream bases (t-invariant addresses) ----
    const bf16_t* obase = wall + (size_t)(768  + 32 * wv + l15) * KEXT + 8 * quad;  // gate o
    const bf16_t* wbase = wall + (size_t)(1024 + 16 * wv + l15) * KEXT + 8 * quad;  // Wo1

    const float bo2v0 = bo2[0], bo2v1 = bo2[1], bo2v2 = bo2[2];

    // ---- ob ring (carried): prefill slices 0,1,2 -> slots 0,1,2 ----
    bf16x8 ob[3][2];
    #pragma unroll
    for (int s = 0; s < 3; ++s)
        #pragma unroll
        for (int h = 0; h < 2; ++h)
            ob[s][h] = *(const bf16x8*)(obase + (size_t)(16 * h) * KEXT + 32 * s);

    // ---- x_0 fragment in regs: quad0 = {m0,m1,m2,1,0..}, quads 1..3 = 0 ----
    bf16x8 xf;
    #pragma unroll
    for (int j = 0; j < 8; ++j) xf[j] = (bf16_t)0.f;
    if (quad == 0) {
        xf[0] = (bf16_t)meta[(size_t)(gb + l15) * 7 + 0];
        xf[1] = (bf16_t)meta[(size_t)(gb + l15) * 7 + 1];
        xf[2] = (bf16_t)meta[(size_t)(gb + l15) * 7 + 2];
        xf[3] = (bf16_t)1.f;
    }

    __syncthreads();   // wg/wo2l ready (one-time full sync is fine here)

    // ================= time loop: G (gates+cell+wrf burst) -> B1 -> Z -> B2 -> Y ======
    for (int i = 0; i < TSTEPS; ++i) {
        const bf16_t (*cur)[HS] = hx[i & 1];         // h_i
        bf16_t (*nxt)[HS]       = hx[(i + 1) & 1];   // h_{i+1} destination

        // -- G (R11 verbatim): gates_i = [h_i|x_i|1] @ Wall^T; kk<8 B from LDS,
        //       kk=8 B = xf regs. ob: same-slot consume-then-refill distance-3. --
        f32x4 acc[4][2];
        #pragma unroll
        for (int g = 0; g < 4; ++g) { acc[g][0] = zero4; acc[g][1] = zero4; }

        #pragma unroll
        for (int kk = 0; kk < 9; ++kk) {
            int ko = 32 * kk + 8 * quad;
            bf16x8 bf = (kk < 8) ? *(const bf16x8*)&cur[l15][ko] : xf;
            #pragma unroll
            for (int h = 0; h < 2; ++h) {
                // kk=8: wg read past col 263 aliases next row's cols; B is zero there -> harmless
                bf16x8 ag = *(const bf16x8*)&wg[32 * wv + 16 * h + l15][ko];
                acc[0][h] = MFMA16(af[0][h][kk], bf, acc[0][h]);
                acc[1][h] = MFMA16(af[1][h][kk], bf, acc[1][h]);
                acc[2][h] = MFMA16(ag,            bf, acc[2][h]);
                acc[3][h] = MFMA16(ob[kk % 3][h], bf, acc[3][h]);
            }
            // refill consumed slot (WAR orders the load after the MFMA reads)
            #pragma unroll
            for (int h = 0; h < 2; ++h)
                ob[kk % 3][h] = *(const bf16x8*)(obase + (size_t)(16 * h) * KEXT
                                                 + 32 * ((kk + 3) % 9));
        }

        // -- cell update (regs) + write h_{i+1}; wrf burst issued mid-cell (acc dying,
        //    loads get cell+barrier+Z-ramp of slack before first consume) --
        bf16x8 wrf[9];
        {
            // half 0
            float hh[4];
            #pragma unroll
            for (int r = 0; r < 4; ++r) {
                float iv = acc[0][0][r], fv = acc[1][0][r];
                float gv = acc[2][0][r], ov = acc[3][0][r];
                float cc = sigm(fv) * c[0][r] + sigm(iv) * tanh_f(gv);
                c[0][r] = cc;
                hh[r] = sigm(ov) * tanh_f(cc);
            }
            int dim = 32 * wv + 4 * quad;
            *(unsigned*)&nxt[l15][dim]     = pk2(hh[0], hh[1]);
            *(unsigned*)&nxt[l15][dim + 2] = pk2(hh[2], hh[3]);
        }
        #pragma unroll
        for (int s = 0; s < 5; ++s) wrf[s] = *(const bf16x8*)(wbase + 32 * s);
        {
            // half 1
            float hh[4];
            #pragma unroll
            for (int r = 0; r < 4; ++r) {
                float iv = acc[0][1][r], fv = acc[1][1][r];
                float gv = acc[2][1][r], ov = acc[3][1][r];
                float cc = sigm(fv) * c[1][r] + sigm(iv) * tanh_f(gv);
                c[1][r] = cc;
                hh[r] = sigm(ov) * tanh_f(cc);
            }
            int dim = 32 * wv + 16 + 4 * quad;
            *(unsigned*)&nxt[l15][dim]     = pk2(hh[0], hh[1]);
            *(unsigned*)&nxt[l15][dim + 2] = pk2(hh[2], hh[3]);
        }
        #pragma unroll
        for (int s = 5; s < 9; ++s) wrf[s] = *(const bf16x8*)(wbase + 32 * s);
        bar_lds();   // B1: h_{i+1} visible; wrf/ob loads stay in flight

        // -- Z: z_i = relu(h_{i+1} @ Wo1ext^T); wave wv -> z-dims [16wv,16wv+16).
        //       Wo1 from wrf (NO global loads); zb[3] rolling same-slot distance-3
        //       (12 TRANSIENT regs, live B1->B2 only); za 2 parallel chains --
        {
            bf16x8 zb[3];
            #pragma unroll
            for (int s = 0; s < 3; ++s)
                zb[s] = *(const bf16x8*)&nxt[l15][32 * s + 8 * quad];
            f32x4 za0 = zero4, za1 = zero4;
            #pragma unroll
            for (int kk = 0; kk < 9; ++kk) {
                if (kk & 1) za1 = MFMA16(wrf[kk], zb[kk % 3], za1);
                else        za0 = MFMA16(wrf[kk], zb[kk % 3], za0);
                if (kk + 3 <= 8)
                    zb[kk % 3] = *(const bf16x8*)&nxt[l15][32 * (kk + 3) + 8 * quad];
            }
            f32x4 za = za0 + za1;
            int zd = 16 * wv + 4 * quad;
            *(unsigned*)&zbuf[l15][zd]     = pk2(fmaxf(za[0], 0.f), fmaxf(za[1], 0.f));
            *(unsigned*)&zbuf[l15][zd + 2] = pk2(fmaxf(za[2], 0.f), fmaxf(za[3], 0.f));
        }
        bar_lds();   // B2: z complete

        // -- Y: ALL waves redundantly y_i = z @ Wo2ext^T (batched reads, 2 chains;
        //       32 TRANSIENT regs, live B2->loop-end only); xf <- x_{i+1}; rotate
        //       out-store. No trailing barrier; NO next-G prefetch (R12's remat cause). --
        {
            bf16x8 w2b[4], zbb[4];
            #pragma unroll
            for (int kk = 0; kk < 4; ++kk) {
                int ko = 32 * kk + 8 * quad;
                w2b[kk] = *(const bf16x8*)&wo2l[l15][ko];
                zbb[kk] = *(const bf16x8*)&zbuf[l15][ko];
            }
            f32x4 ya0 = zero4, ya1 = zero4;
            #pragma unroll
            for (int kk = 0; kk < 4; ++kk) {
                if (kk & 2) ya1 = MFMA16(w2b[kk], zbb[kk], ya1);
                else        ya0 = MFMA16(w2b[kk], zbb[kk], ya0);
            }
            f32x4 yv = ya0 + ya1;
            float y0 = yv[0] + bo2v0, y1 = yv[1] + bo2v1, y2 = yv[2] + bo2v2;
            if (wv == (i & 7) && quad == 0) {   // rotate storer: ack never blocks a barrier
                float* op = out + ((size_t)(gb + l15) * TSTEPS + i) * 3;
                op[0] = y0; op[1] = y1; op[2] = y2;
            }
            if (quad == 0) {
                xf[0] = (bf16_t)y0; xf[1] = (bf16_t)y1; xf[2] = (bf16_t)y2; xf[3] = (bf16_t)1.f;
            }
        }
    }
}

extern "C" void kernel_launch(void* const* d_in, const int* in_sizes, int n_in,
                              void* d_out, int out_size, void* d_ws, size_t ws_size,
                              hipStream_t stream)
{
    const float* meta = (const float*)d_in[0];
    const float* W1   = (const float*)d_in[2];
    const float* b1   = (const float*)d_in[3];
    const float* W2   = (const float*)d_in[4];
    const float* b2   = (const float*)d_in[5];
    const float* Wih  = (const float*)d_in[6];
    const float* Whh  = (const float*)d_in[7];
    const float* bih  = (const float*)d_in[8];
    const float* bhh  = (const float*)d_in[9];
    const float* Wo1  = (const float*)d_in[10];
    const float* bo1  = (const float*)d_in[11];
    const float* Wo2  = (const float*)d_in[12];
    const float* bo2  = (const float*)d_in[13];
    bf16_t* ws  = (bf16_t*)d_ws;
    float*  out = (float*)d_out;

    prep_kernel<<<dim3((WS_ELEMS + 255) / 256), dim3(256), 0, stream>>>(
        W2, b2, Wih, Whh, bih, bhh, Wo1, bo1, Wo2, ws);
    lstm_main<<<dim3(4096 / TILE_B), dim3(512), 0, stream>>>(
        meta, W1, b1, bo2, ws, out);
}